// Round 3
// baseline (284.918 us; speedup 1.0000x reference)
//
#include <hip/hip_runtime.h>

// D = H = W = 128, NUM_STEPS = 7 (MONAI DVF2DDF scaling-and-squaring)
#define DD 128
constexpr int NV = DD * DD * DD;           // 2,097,152 voxels
constexpr float SCALE = 1.0f / 128.0f;     // 2^-NUM_STEPS

__device__ __forceinline__ void unpack_zyx(int tid, int& z, int& y, int& x) {
    x = tid & (DD - 1);
    y = (tid >> 7) & (DD - 1);
    z = tid >> 14;
}

__device__ __forceinline__ float clampc(float v) {
    return fminf(fmaxf(v, 0.0f), (float)(DD - 1));
}

struct Corners {
    int i000, i001, i010, i011, i100, i101, i110, i111;
    float w000, w001, w010, w011, w100, w101, w110, w111;
};

__device__ __forceinline__ Corners corner_setup(float cz, float cy, float cx) {
    float z0f = floorf(cz), y0f = floorf(cy), x0f = floorf(cx);
    float wz = cz - z0f, wy = cy - y0f, wx = cx - x0f;
    int z0 = (int)z0f, y0 = (int)y0f, x0 = (int)x0f;
    int z1 = min(z0 + 1, DD - 1);
    int y1 = min(y0 + 1, DD - 1);
    int x1 = min(x0 + 1, DD - 1);
    float omz = 1.0f - wz, omy = 1.0f - wy, omx = 1.0f - wx;
    int zs0 = z0 << 14, zs1 = z1 << 14;
    int ys0 = y0 << 7,  ys1 = y1 << 7;
    Corners c;
    c.i000 = zs0 + ys0 + x0; c.i001 = zs0 + ys0 + x1;
    c.i010 = zs0 + ys1 + x0; c.i011 = zs0 + ys1 + x1;
    c.i100 = zs1 + ys0 + x0; c.i101 = zs1 + ys0 + x1;
    c.i110 = zs1 + ys1 + x0; c.i111 = zs1 + ys1 + x1;
    c.w000 = omz * omy * omx; c.w001 = omz * omy * wx;
    c.w010 = omz * wy * omx;  c.w011 = omz * wy * wx;
    c.w100 = wz * omy * omx;  c.w101 = wz * omy * wx;
    c.w110 = wz * wy * omx;   c.w111 = wz * wy * wx;
    return c;
}

// ===========================================================================
// FAST PATH: float4-padded interleaved field, one dwordx4 per corner gather
// ===========================================================================

// pack: planar dvf [3,DHW] (coalesced reads) -> float4 field, scaled 2^-7
__global__ __launch_bounds__(256)
void pack_kernel(const float* __restrict__ dvf, float4* __restrict__ dst) {
    int tid = blockIdx.x * blockDim.x + threadIdx.x;
    float4 v;
    v.x = dvf[tid] * SCALE;
    v.y = dvf[tid + NV] * SCALE;
    v.z = dvf[tid + 2 * NV] * SCALE;
    v.w = 0.0f;
    dst[tid] = v;
}

// one step: dst = src + warp(src, src); 8 gathers, each a single ld_dwordx4
__global__ __launch_bounds__(256)
void step4_kernel(const float4* __restrict__ src, float4* __restrict__ dst) {
    int tid = blockIdx.x * blockDim.x + threadIdx.x;
    int z, y, x;
    unpack_zyx(tid, z, y, x);

    float4 s = src[tid];

    Corners c = corner_setup(clampc((float)z + s.x),
                             clampc((float)y + s.y),
                             clampc((float)x + s.z));

    float4 v000 = src[c.i000], v001 = src[c.i001];
    float4 v010 = src[c.i010], v011 = src[c.i011];
    float4 v100 = src[c.i100], v101 = src[c.i101];
    float4 v110 = src[c.i110], v111 = src[c.i111];

    float4 r;
    r.x = s.x + c.w000*v000.x + c.w001*v001.x + c.w010*v010.x + c.w011*v011.x
              + c.w100*v100.x + c.w101*v101.x + c.w110*v110.x + c.w111*v111.x;
    r.y = s.y + c.w000*v000.y + c.w001*v001.y + c.w010*v010.y + c.w011*v011.y
              + c.w100*v100.y + c.w101*v101.y + c.w110*v110.y + c.w111*v111.y;
    r.z = s.z + c.w000*v000.z + c.w001*v001.z + c.w010*v010.z + c.w011*v011.z
              + c.w100*v100.z + c.w101*v101.z + c.w110*v110.z + c.w111*v111.z;
    r.w = 0.0f;
    dst[tid] = r;
}

// step 7 fused with output warps; src lives in d_ws, writes only to d_out
__global__ __launch_bounds__(256)
void step7_final4_kernel(const float4* __restrict__ src,
                         const float* __restrict__ mimg,
                         const float* __restrict__ mlab,
                         float* __restrict__ ddf_out,
                         float* __restrict__ pred_img,
                         float* __restrict__ pred_lab) {
    int tid = blockIdx.x * blockDim.x + threadIdx.x;
    int z, y, x;
    unpack_zyx(tid, z, y, x);

    float4 s = src[tid];

    Corners c = corner_setup(clampc((float)z + s.x),
                             clampc((float)y + s.y),
                             clampc((float)x + s.z));

    float4 v000 = src[c.i000], v001 = src[c.i001];
    float4 v010 = src[c.i010], v011 = src[c.i011];
    float4 v100 = src[c.i100], v101 = src[c.i101];
    float4 v110 = src[c.i110], v111 = src[c.i111];

    float r0 = s.x + c.w000*v000.x + c.w001*v001.x + c.w010*v010.x + c.w011*v011.x
                   + c.w100*v100.x + c.w101*v101.x + c.w110*v110.x + c.w111*v111.x;
    float r1 = s.y + c.w000*v000.y + c.w001*v001.y + c.w010*v010.y + c.w011*v011.y
                   + c.w100*v100.y + c.w101*v101.y + c.w110*v110.y + c.w111*v111.y;
    float r2 = s.z + c.w000*v000.z + c.w001*v001.z + c.w010*v010.z + c.w011*v011.z
                   + c.w100*v100.z + c.w101*v101.z + c.w110*v110.z + c.w111*v111.z;

    ddf_out[tid]          = r0;
    ddf_out[tid + NV]     = r1;
    ddf_out[tid + 2 * NV] = r2;

    float cz = clampc((float)z + r0);
    float cy = clampc((float)y + r1);
    float cx = clampc((float)x + r2);

    {   // bilinear warp of moving_image
        Corners g = corner_setup(cz, cy, cx);
        pred_img[tid] = g.w000*mimg[g.i000] + g.w001*mimg[g.i001]
                      + g.w010*mimg[g.i010] + g.w011*mimg[g.i011]
                      + g.w100*mimg[g.i100] + g.w101*mimg[g.i101]
                      + g.w110*mimg[g.i110] + g.w111*mimg[g.i111];
    }
    {   // nearest warp of moving_label (jnp.round = ties-to-even = rintf)
        int zi = (int)rintf(cz);
        int yi = (int)rintf(cy);
        int xi = (int)rintf(cx);
        pred_lab[tid] = mlab[(zi << 14) + (yi << 7) + xi];
    }
}

// dvf pass-through, float4-vectorized
__global__ __launch_bounds__(256)
void copy_dvf_kernel(const float4* __restrict__ dvf, float4* __restrict__ dvf_out) {
    int tid = blockIdx.x * blockDim.x + threadIdx.x;
    dvf_out[tid] = dvf[tid];
}

// ===========================================================================
// FALLBACK PATH (ws too small): proven R2 float3 structure, no swizzle
// ===========================================================================

__device__ __forceinline__ void trilerp3i(const float* __restrict__ src,
                                          const Corners& c,
                                          float& r0, float& r1, float& r2) {
    const float* p000 = src + 3 * c.i000; const float* p001 = src + 3 * c.i001;
    const float* p010 = src + 3 * c.i010; const float* p011 = src + 3 * c.i011;
    const float* p100 = src + 3 * c.i100; const float* p101 = src + 3 * c.i101;
    const float* p110 = src + 3 * c.i110; const float* p111 = src + 3 * c.i111;
    r0 = c.w000*p000[0] + c.w001*p001[0] + c.w010*p010[0] + c.w011*p011[0]
       + c.w100*p100[0] + c.w101*p101[0] + c.w110*p110[0] + c.w111*p111[0];
    r1 = c.w000*p000[1] + c.w001*p001[1] + c.w010*p010[1] + c.w011*p011[1]
       + c.w100*p100[1] + c.w101*p101[1] + c.w110*p110[1] + c.w111*p111[1];
    r2 = c.w000*p000[2] + c.w001*p001[2] + c.w010*p010[2] + c.w011*p011[2]
       + c.w100*p100[2] + c.w101*p101[2] + c.w110*p110[2] + c.w111*p111[2];
}

__global__ __launch_bounds__(256)
void init3_kernel(const float* __restrict__ dvf, float* __restrict__ A) {
    int tid = blockIdx.x * blockDim.x + threadIdx.x;
    float* p = A + 3 * tid;
    p[0] = dvf[tid] * SCALE;
    p[1] = dvf[tid + NV] * SCALE;
    p[2] = dvf[tid + 2 * NV] * SCALE;
}

__global__ __launch_bounds__(256)
void step3_kernel(const float* __restrict__ src, float* __restrict__ dst) {
    int tid = blockIdx.x * blockDim.x + threadIdx.x;
    int z, y, x;
    unpack_zyx(tid, z, y, x);
    const float* s = src + 3 * tid;
    float d0 = s[0], d1 = s[1], d2 = s[2];
    Corners c = corner_setup(clampc((float)z + d0),
                             clampc((float)y + d1),
                             clampc((float)x + d2));
    float r0, r1, r2;
    trilerp3i(src, c, r0, r1, r2);
    float* p = dst + 3 * tid;
    p[0] = d0 + r0; p[1] = d1 + r1; p[2] = d2 + r2;
}

__global__ __launch_bounds__(256)
void step7_final3_kernel(const float* __restrict__ src,
                         const float* __restrict__ mimg,
                         const float* __restrict__ mlab,
                         float* __restrict__ ddf_out,
                         float* __restrict__ pred_img,
                         float* __restrict__ pred_lab) {
    int tid = blockIdx.x * blockDim.x + threadIdx.x;
    int z, y, x;
    unpack_zyx(tid, z, y, x);
    const float* s = src + 3 * tid;
    float d0 = s[0], d1 = s[1], d2 = s[2];
    Corners c = corner_setup(clampc((float)z + d0),
                             clampc((float)y + d1),
                             clampc((float)x + d2));
    float r0, r1, r2;
    trilerp3i(src, c, r0, r1, r2);
    r0 += d0; r1 += d1; r2 += d2;
    ddf_out[tid]          = r0;
    ddf_out[tid + NV]     = r1;
    ddf_out[tid + 2 * NV] = r2;
    float cz = clampc((float)z + r0);
    float cy = clampc((float)y + r1);
    float cx = clampc((float)x + r2);
    {
        Corners g = corner_setup(cz, cy, cx);
        pred_img[tid] = g.w000*mimg[g.i000] + g.w001*mimg[g.i001]
                      + g.w010*mimg[g.i010] + g.w011*mimg[g.i011]
                      + g.w100*mimg[g.i100] + g.w101*mimg[g.i101]
                      + g.w110*mimg[g.i110] + g.w111*mimg[g.i111];
    }
    {
        int zi = (int)rintf(cz);
        int yi = (int)rintf(cy);
        int xi = (int)rintf(cx);
        pred_lab[tid] = mlab[(zi << 14) + (yi << 7) + xi];
    }
}

// ===========================================================================

extern "C" void kernel_launch(void* const* d_in, const int* in_sizes, int n_in,
                              void* d_out, int out_size, void* d_ws, size_t ws_size,
                              hipStream_t stream) {
    const float* dvf  = (const float*)d_in[0];
    const float* mimg = (const float*)d_in[1];
    // d_in[2] = fixed_image: unused by the reference outputs
    const float* mlab = (const float*)d_in[3];

    float* out      = (float*)d_out;
    float* ddf_out  = out;              // slot 0: ddf  [3,D,H,W]
    float* pred_img = out + 3 * NV;     // slot 1
    float* pred_lab = out + 4 * NV;     // slot 2
    float* dvf_out  = out + 5 * NV;     // slot 3: dvf pass-through

    dim3 block(256);
    dim3 grid(NV / 256);                // 8192 blocks

    if (ws_size >= (size_t)NV * 4 * sizeof(float)) {
        // FAST PATH. Ping-pong: P = d_ws (32 MB), Q = out[4NV, 8NV) (32 MB).
        // Q is dead before step7_final / copy_dvf write over it.
        float4* P = (float4*)d_ws;
        float4* Q = (float4*)(out + 4 * NV);

        pack_kernel<<<grid, block, 0, stream>>>(dvf, P);          // init  -> P
        step4_kernel<<<grid, block, 0, stream>>>(P, Q);           // step 1
        step4_kernel<<<grid, block, 0, stream>>>(Q, P);           // step 2
        step4_kernel<<<grid, block, 0, stream>>>(P, Q);           // step 3
        step4_kernel<<<grid, block, 0, stream>>>(Q, P);           // step 4
        step4_kernel<<<grid, block, 0, stream>>>(P, Q);           // step 5
        step4_kernel<<<grid, block, 0, stream>>>(Q, P);           // step 6 -> P (ws)
        step7_final4_kernel<<<grid, block, 0, stream>>>(P, mimg, mlab,
                                                        ddf_out, pred_img, pred_lab);
        copy_dvf_kernel<<<3 * NV / (4 * 256), block, 0, stream>>>(
            (const float4*)dvf, (float4*)dvf_out);
    } else {
        // FALLBACK (proven R2 structure): float3 ping-pong inside d_out.
        float* A = dvf_out;             // [5NV, 8NV)
        float* B = ddf_out;             // [0, 3NV)
        init3_kernel<<<grid, block, 0, stream>>>(dvf, A);
        step3_kernel<<<grid, block, 0, stream>>>(A, B);           // step 1
        step3_kernel<<<grid, block, 0, stream>>>(B, A);           // step 2
        step3_kernel<<<grid, block, 0, stream>>>(A, B);           // step 3
        step3_kernel<<<grid, block, 0, stream>>>(B, A);           // step 4
        step3_kernel<<<grid, block, 0, stream>>>(A, B);           // step 5
        step3_kernel<<<grid, block, 0, stream>>>(B, A);           // step 6 -> A
        step7_final3_kernel<<<grid, block, 0, stream>>>(A, mimg, mlab,
                                                        ddf_out, pred_img, pred_lab);
        copy_dvf_kernel<<<3 * NV / (4 * 256), block, 0, stream>>>(
            (const float4*)dvf, (float4*)dvf_out);
    }
}

// Round 4
// 280.160 us; speedup vs baseline: 1.0170x; 1.0170x over previous
//
#include <hip/hip_runtime.h>

// D = H = W = 128, NUM_STEPS = 7 (MONAI DVF2DDF scaling-and-squaring)
#define DD 128
constexpr int NV = DD * DD * DD;           // 2,097,152 voxels
constexpr float SCALE = 1.0f / 128.0f;     // 2^-NUM_STEPS

__device__ __forceinline__ float clampc(float v) {
    return fminf(fmaxf(v, 0.0f), (float)(DD - 1));
}

struct Corners {
    int i000, i001, i010, i011, i100, i101, i110, i111;
    float w000, w001, w010, w011, w100, w101, w110, w111;
};

__device__ __forceinline__ Corners corner_setup(float cz, float cy, float cx) {
    float z0f = floorf(cz), y0f = floorf(cy), x0f = floorf(cx);
    float wz = cz - z0f, wy = cy - y0f, wx = cx - x0f;
    int z0 = (int)z0f, y0 = (int)y0f, x0 = (int)x0f;
    int z1 = min(z0 + 1, DD - 1);
    int y1 = min(y0 + 1, DD - 1);
    int x1 = min(x0 + 1, DD - 1);
    float omz = 1.0f - wz, omy = 1.0f - wy, omx = 1.0f - wx;
    int zs0 = z0 << 14, zs1 = z1 << 14;
    int ys0 = y0 << 7,  ys1 = y1 << 7;
    Corners c;
    c.i000 = zs0 + ys0 + x0; c.i001 = zs0 + ys0 + x1;
    c.i010 = zs0 + ys1 + x0; c.i011 = zs0 + ys1 + x1;
    c.i100 = zs1 + ys0 + x0; c.i101 = zs1 + ys0 + x1;
    c.i110 = zs1 + ys1 + x0; c.i111 = zs1 + ys1 + x1;
    c.w000 = omz * omy * omx; c.w001 = omz * omy * wx;
    c.w010 = omz * wy * omx;  c.w011 = omz * wy * wx;
    c.w100 = wz * omy * omx;  c.w101 = wz * omy * wx;
    c.w110 = wz * wy * omx;   c.w111 = wz * wy * wx;
    return c;
}

__device__ __forceinline__ float3 trilerp4(const float4* __restrict__ src,
                                           const Corners& c, float3 base) {
    float4 v000 = src[c.i000], v001 = src[c.i001];
    float4 v010 = src[c.i010], v011 = src[c.i011];
    float4 v100 = src[c.i100], v101 = src[c.i101];
    float4 v110 = src[c.i110], v111 = src[c.i111];
    float3 r;
    r.x = base.x + c.w000*v000.x + c.w001*v001.x + c.w010*v010.x + c.w011*v011.x
                 + c.w100*v100.x + c.w101*v101.x + c.w110*v110.x + c.w111*v111.x;
    r.y = base.y + c.w000*v000.y + c.w001*v001.y + c.w010*v010.y + c.w011*v011.y
                 + c.w100*v100.y + c.w101*v101.y + c.w110*v110.y + c.w111*v111.y;
    r.z = base.z + c.w000*v000.z + c.w001*v001.z + c.w010*v010.z + c.w011*v011.z
                 + c.w100*v100.z + c.w101*v101.z + c.w110*v110.z + c.w111*v111.z;
    return r;
}

// ===========================================================================
// FAST PATH: float4 field; step kernels process 2 voxels/thread (z, z+1)
// for 2x memory-level parallelism per wave (latency-bound hypothesis).
// ===========================================================================

// pack: planar dvf [3,DHW] (coalesced reads) -> float4 field, scaled 2^-7
__global__ __launch_bounds__(256)
void pack_kernel(const float* __restrict__ dvf, float4* __restrict__ dst) {
    int tid = blockIdx.x * blockDim.x + threadIdx.x;
    float4 v;
    v.x = dvf[tid] * SCALE;
    v.y = dvf[tid + NV] * SCALE;
    v.z = dvf[tid + 2 * NV] * SCALE;
    v.w = 0.0f;
    dst[tid] = v;
}

// one step, 2 voxels per thread: (z,y,x) and (z+1,y,x)
__global__ __launch_bounds__(256)
void step_pair_kernel(const float4* __restrict__ src, float4* __restrict__ dst) {
    int t = blockIdx.x * blockDim.x + threadIdx.x;   // t in [0, NV/2)
    int x  = t & (DD - 1);
    int y  = (t >> 7) & (DD - 1);
    int zh = t >> 14;                                // 0..63
    int z  = zh << 1;

    int idxA = (z << 14) + (y << 7) + x;
    int idxB = idxA + (1 << 14);

    // two independent own-loads issue back-to-back
    float4 sA = src[idxA];
    float4 sB = src[idxB];

    Corners cA = corner_setup(clampc((float)z + sA.x),
                              clampc((float)y + sA.y),
                              clampc((float)x + sA.z));
    Corners cB = corner_setup(clampc((float)(z + 1) + sB.x),
                              clampc((float)y + sB.y),
                              clampc((float)x + sB.z));

    // 16 independent gathers in flight; corner lines overlap ~50% in z
    float3 rA = trilerp4(src, cA, make_float3(sA.x, sA.y, sA.z));
    float3 rB = trilerp4(src, cB, make_float3(sB.x, sB.y, sB.z));

    dst[idxA] = make_float4(rA.x, rA.y, rA.z, 0.0f);
    dst[idxB] = make_float4(rB.x, rB.y, rB.z, 0.0f);
}

// step 7 fused with output warps AND dvf pass-through
__global__ __launch_bounds__(256)
void step7_final4_kernel(const float4* __restrict__ src,
                         const float* __restrict__ mimg,
                         const float* __restrict__ mlab,
                         const float* __restrict__ dvf,
                         float* __restrict__ ddf_out,
                         float* __restrict__ pred_img,
                         float* __restrict__ pred_lab,
                         float* __restrict__ dvf_out) {
    int tid = blockIdx.x * blockDim.x + threadIdx.x;
    int x = tid & (DD - 1);
    int y = (tid >> 7) & (DD - 1);
    int z = tid >> 14;

    float4 s = src[tid];
    // dvf pass-through (independent stream, overlaps gather latency)
    float dv0 = dvf[tid], dv1 = dvf[tid + NV], dv2 = dvf[tid + 2 * NV];

    Corners c = corner_setup(clampc((float)z + s.x),
                             clampc((float)y + s.y),
                             clampc((float)x + s.z));
    float3 r = trilerp4(src, c, make_float3(s.x, s.y, s.z));

    ddf_out[tid]          = r.x;
    ddf_out[tid + NV]     = r.y;
    ddf_out[tid + 2 * NV] = r.z;
    dvf_out[tid]          = dv0;
    dvf_out[tid + NV]     = dv1;
    dvf_out[tid + 2 * NV] = dv2;

    float cz = clampc((float)z + r.x);
    float cy = clampc((float)y + r.y);
    float cx = clampc((float)x + r.z);

    {   // bilinear warp of moving_image
        Corners g = corner_setup(cz, cy, cx);
        pred_img[tid] = g.w000*mimg[g.i000] + g.w001*mimg[g.i001]
                      + g.w010*mimg[g.i010] + g.w011*mimg[g.i011]
                      + g.w100*mimg[g.i100] + g.w101*mimg[g.i101]
                      + g.w110*mimg[g.i110] + g.w111*mimg[g.i111];
    }
    {   // nearest warp of moving_label (jnp.round = ties-to-even = rintf)
        int zi = (int)rintf(cz);
        int yi = (int)rintf(cy);
        int xi = (int)rintf(cx);
        pred_lab[tid] = mlab[(zi << 14) + (yi << 7) + xi];
    }
}

// ===========================================================================
// FALLBACK PATH (ws too small): proven R2 float3 structure
// ===========================================================================

__device__ __forceinline__ void trilerp3i(const float* __restrict__ src,
                                          const Corners& c,
                                          float& r0, float& r1, float& r2) {
    const float* p000 = src + 3 * c.i000; const float* p001 = src + 3 * c.i001;
    const float* p010 = src + 3 * c.i010; const float* p011 = src + 3 * c.i011;
    const float* p100 = src + 3 * c.i100; const float* p101 = src + 3 * c.i101;
    const float* p110 = src + 3 * c.i110; const float* p111 = src + 3 * c.i111;
    r0 = c.w000*p000[0] + c.w001*p001[0] + c.w010*p010[0] + c.w011*p011[0]
       + c.w100*p100[0] + c.w101*p101[0] + c.w110*p110[0] + c.w111*p111[0];
    r1 = c.w000*p000[1] + c.w001*p001[1] + c.w010*p010[1] + c.w011*p011[1]
       + c.w100*p100[1] + c.w101*p101[1] + c.w110*p110[1] + c.w111*p111[1];
    r2 = c.w000*p000[2] + c.w001*p001[2] + c.w010*p010[2] + c.w011*p011[2]
       + c.w100*p100[2] + c.w101*p101[2] + c.w110*p110[2] + c.w111*p111[2];
}

__global__ __launch_bounds__(256)
void init3_kernel(const float* __restrict__ dvf, float* __restrict__ A) {
    int tid = blockIdx.x * blockDim.x + threadIdx.x;
    float* p = A + 3 * tid;
    p[0] = dvf[tid] * SCALE;
    p[1] = dvf[tid + NV] * SCALE;
    p[2] = dvf[tid + 2 * NV] * SCALE;
}

__global__ __launch_bounds__(256)
void step3_kernel(const float* __restrict__ src, float* __restrict__ dst) {
    int tid = blockIdx.x * blockDim.x + threadIdx.x;
    int x = tid & (DD - 1);
    int y = (tid >> 7) & (DD - 1);
    int z = tid >> 14;
    const float* s = src + 3 * tid;
    float d0 = s[0], d1 = s[1], d2 = s[2];
    Corners c = corner_setup(clampc((float)z + d0),
                             clampc((float)y + d1),
                             clampc((float)x + d2));
    float r0, r1, r2;
    trilerp3i(src, c, r0, r1, r2);
    float* p = dst + 3 * tid;
    p[0] = d0 + r0; p[1] = d1 + r1; p[2] = d2 + r2;
}

__global__ __launch_bounds__(256)
void step7_final3_kernel(const float* __restrict__ src,
                         const float* __restrict__ mimg,
                         const float* __restrict__ mlab,
                         const float* __restrict__ dvf,
                         float* __restrict__ ddf_out,
                         float* __restrict__ pred_img,
                         float* __restrict__ pred_lab,
                         float* __restrict__ dvf_out) {
    int tid = blockIdx.x * blockDim.x + threadIdx.x;
    int x = tid & (DD - 1);
    int y = (tid >> 7) & (DD - 1);
    int z = tid >> 14;
    const float* s = src + 3 * tid;
    float d0 = s[0], d1 = s[1], d2 = s[2];
    Corners c = corner_setup(clampc((float)z + d0),
                             clampc((float)y + d1),
                             clampc((float)x + d2));
    float r0, r1, r2;
    trilerp3i(src, c, r0, r1, r2);
    r0 += d0; r1 += d1; r2 += d2;
    ddf_out[tid]          = r0;
    ddf_out[tid + NV]     = r1;
    ddf_out[tid + 2 * NV] = r2;
    dvf_out[tid]          = dvf[tid];
    dvf_out[tid + NV]     = dvf[tid + NV];
    dvf_out[tid + 2 * NV] = dvf[tid + 2 * NV];
    float cz = clampc((float)z + r0);
    float cy = clampc((float)y + r1);
    float cx = clampc((float)x + r2);
    {
        Corners g = corner_setup(cz, cy, cx);
        pred_img[tid] = g.w000*mimg[g.i000] + g.w001*mimg[g.i001]
                      + g.w010*mimg[g.i010] + g.w011*mimg[g.i011]
                      + g.w100*mimg[g.i100] + g.w101*mimg[g.i101]
                      + g.w110*mimg[g.i110] + g.w111*mimg[g.i111];
    }
    {
        int zi = (int)rintf(cz);
        int yi = (int)rintf(cy);
        int xi = (int)rintf(cx);
        pred_lab[tid] = mlab[(zi << 14) + (yi << 7) + xi];
    }
}

// ===========================================================================

extern "C" void kernel_launch(void* const* d_in, const int* in_sizes, int n_in,
                              void* d_out, int out_size, void* d_ws, size_t ws_size,
                              hipStream_t stream) {
    const float* dvf  = (const float*)d_in[0];
    const float* mimg = (const float*)d_in[1];
    // d_in[2] = fixed_image: unused by the reference outputs
    const float* mlab = (const float*)d_in[3];

    float* out      = (float*)d_out;
    float* ddf_out  = out;              // slot 0: ddf  [3,D,H,W]
    float* pred_img = out + 3 * NV;     // slot 1
    float* pred_lab = out + 4 * NV;     // slot 2
    float* dvf_out  = out + 5 * NV;     // slot 3: dvf pass-through

    dim3 block(256);
    dim3 grid(NV / 256);                // 8192 blocks
    dim3 gridh(NV / 512);               // 4096 blocks (2 voxels/thread)

    if (ws_size >= (size_t)NV * 4 * sizeof(float)) {
        // FAST PATH. Ping-pong: P = d_ws (32 MB), Q = out[4NV, 8NV) (32 MB).
        // Q is dead before step7_final writes over it (lab slot + dvf slot).
        float4* P = (float4*)d_ws;
        float4* Q = (float4*)(out + 4 * NV);

        pack_kernel<<<grid, block, 0, stream>>>(dvf, P);               // init -> P
        step_pair_kernel<<<gridh, block, 0, stream>>>(P, Q);           // step 1
        step_pair_kernel<<<gridh, block, 0, stream>>>(Q, P);           // step 2
        step_pair_kernel<<<gridh, block, 0, stream>>>(P, Q);           // step 3
        step_pair_kernel<<<gridh, block, 0, stream>>>(Q, P);           // step 4
        step_pair_kernel<<<gridh, block, 0, stream>>>(P, Q);           // step 5
        step_pair_kernel<<<gridh, block, 0, stream>>>(Q, P);           // step 6 -> P
        step7_final4_kernel<<<grid, block, 0, stream>>>(P, mimg, mlab, dvf,
                                                        ddf_out, pred_img,
                                                        pred_lab, dvf_out);
    } else {
        // FALLBACK: float3 ping-pong inside d_out.
        float* A = dvf_out;             // [5NV, 8NV)
        float* B = ddf_out;             // [0, 3NV)
        init3_kernel<<<grid, block, 0, stream>>>(dvf, A);
        step3_kernel<<<grid, block, 0, stream>>>(A, B);           // step 1
        step3_kernel<<<grid, block, 0, stream>>>(B, A);           // step 2
        step3_kernel<<<grid, block, 0, stream>>>(A, B);           // step 3
        step3_kernel<<<grid, block, 0, stream>>>(B, A);           // step 4
        step3_kernel<<<grid, block, 0, stream>>>(A, B);           // step 5
        step3_kernel<<<grid, block, 0, stream>>>(B, A);           // step 6 -> A
        step7_final3_kernel<<<grid, block, 0, stream>>>(A, mimg, mlab, dvf,
                                                        ddf_out, pred_img,
                                                        pred_lab, dvf_out);
    }
}